// Round 1
// 340.072 us; speedup vs baseline: 2.3803x; 2.3803x over previous
//
#include <hip/hip_runtime.h>
#include <math.h>

#define N_NODES 40000
#define N_EDGES 640000
#define NFEAT 128
#define NHID 128
#define NCLASS 40
#define SCAN_BLOCKS ((N_NODES + 255) / 256)   // 157

__device__ __forceinline__ float wave_sum(float v) {
    #pragma unroll
    for (int m = 1; m < 64; m <<= 1) v += __shfl_xor(v, m, 64);
    return v;
}
__device__ __forceinline__ float wave_max(float v) {
    #pragma unroll
    for (int m = 1; m < 64; m <<= 1) v = fmaxf(v, __shfl_xor(v, m, 64));
    return v;
}

// h0 = layer_norm(x, g, b); one wave per 128-wide row, float2 per lane
__global__ __launch_bounds__(256) void ln0_kernel(const float* __restrict__ x,
        const float* __restrict__ g, const float* __restrict__ b,
        float* __restrict__ out) {
    int row = blockIdx.x * 4 + (threadIdx.x >> 6);
    int lane = threadIdx.x & 63;
    float2 v = ((const float2*)(x + (size_t)row * 128))[lane];
    float mu = wave_sum(v.x + v.y) * (1.0f / 128.0f);
    float dx = v.x - mu, dy = v.y - mu;
    float var = wave_sum(dx * dx + dy * dy) * (1.0f / 128.0f);
    float rs = rsqrtf(var + 1e-5f);
    float2 gv = ((const float2*)g)[lane];
    float2 bv = ((const float2*)b)[lane];
    float2 o;
    o.x = dx * rs * gv.x + bv.x;
    o.y = dy * rs * gv.y + bv.y;
    ((float2*)(out + (size_t)row * 128))[lane] = o;
}

// Build transposed weight layouts:
//   Wt1[k][c], c in [0,256): c<128 -> W0l[c][k], else W0r[c-128][k]
//   Wt2[k][c], c in [0,80):  c<40  -> W1l[c][k], else W1r[c-40][k]
__global__ __launch_bounds__(256) void prep_w(const float* __restrict__ W0l,
        const float* __restrict__ W0r, const float* __restrict__ W1l,
        const float* __restrict__ W1r, float* __restrict__ Wt1,
        float* __restrict__ Wt2) {
    int i = blockIdx.x * 256 + threadIdx.x;
    if (i < 128 * 256) {
        int k = i >> 8, c = i & 255;
        Wt1[i] = (c < 128) ? W0l[c * 128 + k] : W0r[(c - 128) * 128 + k];
    } else {
        int j = i - 128 * 256;
        if (j < 128 * 80) {
            int k = j / 80, c = j % 80;
            Wt2[j] = (c < 40) ? W1l[c * 128 + k] : W1r[(c - 40) * 128 + k];
        }
    }
}

// ---------------- CSR-by-destination build ----------------

__global__ __launch_bounds__(256) void zero_deg(int* __restrict__ deg) {
    int i = blockIdx.x * 256 + threadIdx.x;
    if (i < N_NODES) deg[i] = 0;
}

__global__ __launch_bounds__(256) void deg_kernel(const int* __restrict__ ei,
        int* __restrict__ deg) {
    int e = blockIdx.x * 256 + threadIdx.x;
    atomicAdd(&deg[ei[N_EDGES + e]], 1);
}

// block-local exclusive scan of deg -> rowStart (local), per-block totals
__global__ __launch_bounds__(256) void scanA(const int* __restrict__ deg,
        int* __restrict__ rowStart, int* __restrict__ blockSums) {
    int i = blockIdx.x * 256 + threadIdx.x;
    int lane = threadIdx.x & 63, wid = threadIdx.x >> 6;
    int v = (i < N_NODES) ? deg[i] : 0;
    int s = v;
    #pragma unroll
    for (int m = 1; m < 64; m <<= 1) {
        int u = __shfl_up(s, m, 64);
        if (lane >= m) s += u;
    }
    __shared__ int wsum[4];
    if (lane == 63) wsum[wid] = s;
    __syncthreads();
    int off = 0;
    for (int w = 0; w < wid; ++w) off += wsum[w];
    if (i < N_NODES) rowStart[i] = off + s - v;   // local exclusive
    if (threadIdx.x == 255) blockSums[blockIdx.x] = off + s;
}

// exclusive scan of 157 block sums (single block)
__global__ __launch_bounds__(256) void scanB(const int* __restrict__ blockSums,
        int* __restrict__ blockOffs) {
    int t = threadIdx.x;
    int lane = t & 63, wid = t >> 6;
    int v = (t < SCAN_BLOCKS) ? blockSums[t] : 0;
    int s = v;
    #pragma unroll
    for (int m = 1; m < 64; m <<= 1) {
        int u = __shfl_up(s, m, 64);
        if (lane >= m) s += u;
    }
    __shared__ int wsum[4];
    if (lane == 63) wsum[wid] = s;
    __syncthreads();
    int off = 0;
    for (int w = 0; w < wid; ++w) off += wsum[w];
    blockOffs[t] = off + s - v;
}

// add block offsets; init cursor = rowStart; set sentinel
__global__ __launch_bounds__(256) void scanC(const int* __restrict__ blockOffs,
        int* __restrict__ rowStart, int* __restrict__ cursor) {
    int i = blockIdx.x * 256 + threadIdx.x;
    if (i < N_NODES) {
        int v = rowStart[i] + blockOffs[blockIdx.x];
        rowStart[i] = v;
        cursor[i] = v;
    }
    if (i == 0) rowStart[N_NODES] = N_EDGES;
}

// bucket-fill (src, weight) pairs sorted by destination
__global__ __launch_bounds__(256) void fill_kernel(const int* __restrict__ ei,
        const float* __restrict__ ew, int* __restrict__ cursor,
        int2* __restrict__ sSW) {
    int e = blockIdx.x * 256 + threadIdx.x;
    int s = ei[e];
    int d = ei[N_EDGES + e];
    float w = ew[e];
    int idx = atomicAdd(&cursor[d], 1);
    sSW[idx] = make_int2(s, __float_as_int(w));
}

// ---------------- main pipeline ----------------

// hl = h0 @ W0l^T + b0l ; agg(init) = h0 @ W0r^T
__global__ __launch_bounds__(256) void gemm1_kernel(const float* __restrict__ h0,
        const float* __restrict__ Wt1, const float* __restrict__ b0l,
        float* __restrict__ hl, float* __restrict__ agg) {
    int c = threadIdx.x;
    int r0 = blockIdx.x * 8;
    float acc[8] = {0.f, 0.f, 0.f, 0.f, 0.f, 0.f, 0.f, 0.f};
    const float* xp = h0 + (size_t)r0 * 128;
    for (int k = 0; k < 128; ++k) {
        float w = Wt1[k * 256 + c];
        #pragma unroll
        for (int i = 0; i < 8; ++i)
            acc[i] = fmaf(xp[i * 128 + k], w, acc[i]);
    }
    if (c < 128) {
        float bias = b0l[c];
        #pragma unroll
        for (int i = 0; i < 8; ++i)
            hl[(size_t)(r0 + i) * 128 + c] = acc[i] + bias;
    } else {
        int cc = c - 128;
        #pragma unroll
        for (int i = 0; i < 8; ++i)
            agg[(size_t)(r0 + i) * 128 + cc] = acc[i];
    }
}

// agg[d] += sum_e hl[src_e]*w_e over d's incident edges; wave per node, no atomics
__global__ __launch_bounds__(256) void gather1_kernel(const int* __restrict__ rowStart,
        const int2* __restrict__ sSW, const float* __restrict__ hl,
        float* __restrict__ agg) {
    int row = blockIdx.x * 4 + (threadIdx.x >> 6);
    int lane = threadIdx.x & 63;
    int beg = rowStart[row], end = rowStart[row + 1];
    float2 acc = ((const float2*)(agg + (size_t)row * 128))[lane];  // root term
    int e = beg;
    for (; e + 2 <= end; e += 2) {
        int2 p0 = sSW[e];
        int2 p1 = sSW[e + 1];
        float2 v0 = ((const float2*)(hl + (size_t)p0.x * 128))[lane];
        float2 v1 = ((const float2*)(hl + (size_t)p1.x * 128))[lane];
        float w0 = __int_as_float(p0.y), w1 = __int_as_float(p1.y);
        acc.x = fmaf(v0.x, w0, acc.x);
        acc.y = fmaf(v0.y, w0, acc.y);
        acc.x = fmaf(v1.x, w1, acc.x);
        acc.y = fmaf(v1.y, w1, acc.y);
    }
    if (e < end) {
        int2 p = sSW[e];
        float2 v = ((const float2*)(hl + (size_t)p.x * 128))[lane];
        float w = __int_as_float(p.y);
        acc.x = fmaf(v.x, w, acc.x);
        acc.y = fmaf(v.y, w, acc.y);
    }
    ((float2*)(agg + (size_t)row * 128))[lane] = acc;
}

// h2 = relu(layer_norm(l2normalize(agg), g, b)) ; wave per row
__global__ __launch_bounds__(256) void mid_kernel(const float* __restrict__ agg,
        const float* __restrict__ g, const float* __restrict__ b,
        float* __restrict__ h2) {
    int row = blockIdx.x * 4 + (threadIdx.x >> 6);
    int lane = threadIdx.x & 63;
    float2 v = ((const float2*)(agg + (size_t)row * 128))[lane];
    float nrm = sqrtf(wave_sum(v.x * v.x + v.y * v.y));
    float inv = 1.0f / fmaxf(nrm, 1e-12f);
    v.x *= inv; v.y *= inv;
    float mu = wave_sum(v.x + v.y) * (1.0f / 128.0f);
    float dx = v.x - mu, dy = v.y - mu;
    float var = wave_sum(dx * dx + dy * dy) * (1.0f / 128.0f);
    float rs = rsqrtf(var + 1e-5f);
    float2 gv = ((const float2*)g)[lane];
    float2 bv = ((const float2*)b)[lane];
    float2 o;
    o.x = fmaxf(dx * rs * gv.x + bv.x, 0.0f);
    o.y = fmaxf(dy * rs * gv.y + bv.y, 0.0f);
    ((float2*)(h2 + (size_t)row * 128))[lane] = o;
}

// gl = h2 @ W1l^T + b1l ; agg2(init) = h2 @ W1r^T
__global__ __launch_bounds__(256) void gemm2_kernel(const float* __restrict__ h2,
        const float* __restrict__ Wt2, const float* __restrict__ b1l,
        float* __restrict__ gl, float* __restrict__ agg2) {
    int c = threadIdx.x & 127;
    int rg = threadIdx.x >> 7;
    int r0 = blockIdx.x * 16 + rg * 8;
    if (c >= 80) return;
    float acc[8] = {0.f, 0.f, 0.f, 0.f, 0.f, 0.f, 0.f, 0.f};
    const float* xp = h2 + (size_t)r0 * 128;
    for (int k = 0; k < 128; ++k) {
        float w = Wt2[k * 80 + c];
        #pragma unroll
        for (int i = 0; i < 8; ++i)
            acc[i] = fmaf(xp[i * 128 + k], w, acc[i]);
    }
    if (c < 40) {
        float bias = b1l[c];
        #pragma unroll
        for (int i = 0; i < 8; ++i)
            gl[(size_t)(r0 + i) * 40 + c] = acc[i] + bias;
    } else {
        int cc = c - 40;
        #pragma unroll
        for (int i = 0; i < 8; ++i)
            agg2[(size_t)(r0 + i) * 40 + cc] = acc[i];
    }
}

// agg2[d] += sum_e gl[src_e]*w_e ; wave per node, lanes 0..39, no atomics
__global__ __launch_bounds__(256) void gather2_kernel(const int* __restrict__ rowStart,
        const int2* __restrict__ sSW, const float* __restrict__ gl,
        float* __restrict__ agg2) {
    int row = blockIdx.x * 4 + (threadIdx.x >> 6);
    int lane = threadIdx.x & 63;
    bool act = lane < 40;
    int beg = rowStart[row], end = rowStart[row + 1];
    float acc = act ? agg2[(size_t)row * 40 + lane] : 0.0f;  // root term
    int e = beg;
    for (; e + 2 <= end; e += 2) {
        int2 p0 = sSW[e];
        int2 p1 = sSW[e + 1];
        // lanes >= 40 read in-bounds garbage (buffer is 5.12M floats), never stored
        float v0 = gl[(size_t)p0.x * 40 + lane];
        float v1 = gl[(size_t)p1.x * 40 + lane];
        acc = fmaf(v0, __int_as_float(p0.y), acc);
        acc = fmaf(v1, __int_as_float(p1.y), acc);
    }
    if (e < end) {
        int2 p = sSW[e];
        float v = gl[(size_t)p.x * 40 + lane];
        acc = fmaf(v, __int_as_float(p.y), acc);
    }
    if (act) agg2[(size_t)row * 40 + lane] = acc;
}

// out = log_softmax(l2normalize(agg2)) ; wave per row, lanes 0..39
__global__ __launch_bounds__(256) void final_kernel(const float* __restrict__ agg2,
        float* __restrict__ out) {
    int row = blockIdx.x * 4 + (threadIdx.x >> 6);
    int lane = threadIdx.x & 63;
    bool act = lane < 40;
    float v = act ? agg2[(size_t)row * 40 + lane] : 0.0f;
    float nrm = sqrtf(wave_sum(v * v));
    float o = v / fmaxf(nrm, 1e-12f);
    float m = wave_max(act ? o : -INFINITY);
    float s = wave_sum(act ? expf(o - m) : 0.0f);
    float ls = logf(s);
    if (act) out[(size_t)row * 40 + lane] = o - m - ls;
}

extern "C" void kernel_launch(void* const* d_in, const int* in_sizes, int n_in,
                              void* d_out, int out_size, void* d_ws, size_t ws_size,
                              hipStream_t stream) {
    const float* x    = (const float*)d_in[0];
    const int*   ei   = (const int*)d_in[1];
    const float* ew   = (const float*)d_in[2];
    const float* ln0g = (const float*)d_in[3];
    const float* ln0b = (const float*)d_in[4];
    const float* W0l  = (const float*)d_in[5];
    const float* b0l  = (const float*)d_in[6];
    const float* W0r  = (const float*)d_in[7];
    const float* ln1g = (const float*)d_in[8];
    const float* ln1b = (const float*)d_in[9];
    const float* W1l  = (const float*)d_in[10];
    const float* b1l  = (const float*)d_in[11];
    const float* W1r  = (const float*)d_in[12];
    float* out = (float*)d_out;

    float* ws = (float*)d_ws;
    const size_t NBUF = (size_t)N_NODES * 128;  // 5.12M floats
    float* bufA = ws;                 // h0, later h2
    float* bufB = bufA + NBUF;        // hl, later gl
    float* bufC = bufB + NBUF;        // agg, later agg2
    float* Wt1  = bufC + NBUF;        // 128*256
    float* Wt2  = Wt1 + 128 * 256;    // 128*80
    // CSR scratch (ints/pairs) after the float region
    int*  deg       = (int*)(Wt2 + 128 * 80);
    int*  rowStart  = deg + N_NODES;            // N_NODES+1
    int*  cursor    = rowStart + N_NODES + 1;
    int*  blockSums = cursor + N_NODES;         // 256 (157 used)
    int*  blockOffs = blockSums + 256;          // 256
    int2* sSW       = (int2*)(blockOffs + 256); // N_EDGES pairs (dst-sorted src,w)

    // --- CSR build (reused by both conv layers) ---
    zero_deg<<<SCAN_BLOCKS, 256, 0, stream>>>(deg);
    deg_kernel<<<N_EDGES / 256, 256, 0, stream>>>(ei, deg);
    scanA<<<SCAN_BLOCKS, 256, 0, stream>>>(deg, rowStart, blockSums);
    scanB<<<1, 256, 0, stream>>>(blockSums, blockOffs);
    scanC<<<SCAN_BLOCKS, 256, 0, stream>>>(blockOffs, rowStart, cursor);
    fill_kernel<<<N_EDGES / 256, 256, 0, stream>>>(ei, ew, cursor, sSW);

    // --- pipeline ---
    ln0_kernel<<<N_NODES / 4, 256, 0, stream>>>(x, ln0g, ln0b, bufA);
    prep_w<<<(128 * 256 + 128 * 80) / 256, 256, 0, stream>>>(W0l, W0r, W1l, W1r, Wt1, Wt2);
    gemm1_kernel<<<N_NODES / 8, 256, 0, stream>>>(bufA, Wt1, b0l, bufB, bufC);
    gather1_kernel<<<N_NODES / 4, 256, 0, stream>>>(rowStart, sSW, bufB, bufC);
    mid_kernel<<<N_NODES / 4, 256, 0, stream>>>(bufC, ln1g, ln1b, bufA);
    gemm2_kernel<<<N_NODES / 16, 256, 0, stream>>>(bufA, Wt2, b1l, bufB, bufC);
    gather2_kernel<<<N_NODES / 4, 256, 0, stream>>>(rowStart, sSW, bufB, bufC);
    final_kernel<<<N_NODES / 4, 256, 0, stream>>>(bufC, out);
}

// Round 2
// 239.369 us; speedup vs baseline: 3.3817x; 1.4207x over previous
//
#include <hip/hip_runtime.h>
#include <math.h>

#define N_NODES 40000
#define N_EDGES 640000
#define SCAN_BLOCKS ((N_NODES + 255) / 256)   // 157

typedef __attribute__((ext_vector_type(8))) short short8;   // 8 bf16 (A/B frag)
typedef __attribute__((ext_vector_type(4))) float f32x4;    // C/D frag

__device__ __forceinline__ unsigned short f2bf(float f) {
    union { float f; unsigned u; } v; v.f = f;
    unsigned r = (v.u + 0x7FFFu + ((v.u >> 16) & 1u)) >> 16;  // RNE
    return (unsigned short)r;
}
__device__ __forceinline__ float bf2f(unsigned short h) {
    union { unsigned u; float f; } v; v.u = ((unsigned)h) << 16;
    return v.f;
}

__device__ __forceinline__ float wave_sum(float v) {
    #pragma unroll
    for (int m = 1; m < 64; m <<= 1) v += __shfl_xor(v, m, 64);
    return v;
}
__device__ __forceinline__ float wave_max(float v) {
    #pragma unroll
    for (int m = 1; m < 64; m <<= 1) v = fmaxf(v, __shfl_xor(v, m, 64));
    return v;
}

// h0 = layer_norm(x,g,b) -> split bf16 planes (hi, lo); wave per 128-wide row
__global__ __launch_bounds__(256) void ln0_kernel(const float* __restrict__ x,
        const float* __restrict__ g, const float* __restrict__ b,
        unsigned short* __restrict__ h0h, unsigned short* __restrict__ h0l) {
    int row = blockIdx.x * 4 + (threadIdx.x >> 6);
    int lane = threadIdx.x & 63;
    float2 v = ((const float2*)(x + (size_t)row * 128))[lane];
    float mu = wave_sum(v.x + v.y) * (1.0f / 128.0f);
    float dx = v.x - mu, dy = v.y - mu;
    float var = wave_sum(dx * dx + dy * dy) * (1.0f / 128.0f);
    float rs = rsqrtf(var + 1e-5f);
    float2 gv = ((const float2*)g)[lane];
    float2 bv = ((const float2*)b)[lane];
    float ox = dx * rs * gv.x + bv.x;
    float oy = dy * rs * gv.y + bv.y;
    ushort2 hv, lv;
    hv.x = f2bf(ox); hv.y = f2bf(oy);
    lv.x = f2bf(ox - bf2f(hv.x)); lv.y = f2bf(oy - bf2f(hv.y));
    ((ushort2*)(h0h + (size_t)row * 128))[lane] = hv;
    ((ushort2*)(h0l + (size_t)row * 128))[lane] = lv;
}

// Weights -> col-major [c][k] split bf16 planes.
// Wt1 (256 cols): c<128 -> W0l[c][k], else W0r[c-128][k]
// Wt2 (80 cols):  c<40  -> W1l[c][k], else W1r[c-40][k]
__global__ __launch_bounds__(256) void prep_w(const float* __restrict__ W0l,
        const float* __restrict__ W0r, const float* __restrict__ W1l,
        const float* __restrict__ W1r,
        unsigned short* __restrict__ Wt1h, unsigned short* __restrict__ Wt1l,
        unsigned short* __restrict__ Wt2h, unsigned short* __restrict__ Wt2l) {
    int i = blockIdx.x * 256 + threadIdx.x;   // 0..43007
    float w; unsigned short *ph, *pl; int idx;
    if (i < 256 * 128) {
        int c = i >> 7, k = i & 127;
        w = (c < 128) ? W0l[c * 128 + k] : W0r[(c - 128) * 128 + k];
        ph = Wt1h; pl = Wt1l; idx = i;
    } else {
        int j = i - 256 * 128;
        int c = j >> 7, k = j & 127;
        w = (c < 40) ? W1l[c * 128 + k] : W1r[(c - 40) * 128 + k];
        ph = Wt2h; pl = Wt2l; idx = j;
    }
    unsigned short hi = f2bf(w);
    ph[idx] = hi;
    pl[idx] = f2bf(w - bf2f(hi));
}

// ---------------- CSR-by-destination build ----------------

__global__ __launch_bounds__(256) void zero_deg(int* __restrict__ deg) {
    int i = blockIdx.x * 256 + threadIdx.x;
    if (i < N_NODES) deg[i] = 0;
}

__global__ __launch_bounds__(256) void deg_kernel(const int* __restrict__ ei,
        int* __restrict__ deg) {
    int e = blockIdx.x * 256 + threadIdx.x;
    atomicAdd(&deg[ei[N_EDGES + e]], 1);
}

__global__ __launch_bounds__(256) void scanA(const int* __restrict__ deg,
        int* __restrict__ rowStart, int* __restrict__ blockSums) {
    int i = blockIdx.x * 256 + threadIdx.x;
    int lane = threadIdx.x & 63, wid = threadIdx.x >> 6;
    int v = (i < N_NODES) ? deg[i] : 0;
    int s = v;
    #pragma unroll
    for (int m = 1; m < 64; m <<= 1) {
        int u = __shfl_up(s, m, 64);
        if (lane >= m) s += u;
    }
    __shared__ int wsum[4];
    if (lane == 63) wsum[wid] = s;
    __syncthreads();
    int off = 0;
    for (int w = 0; w < wid; ++w) off += wsum[w];
    if (i < N_NODES) rowStart[i] = off + s - v;
    if (threadIdx.x == 255) blockSums[blockIdx.x] = off + s;
}

__global__ __launch_bounds__(256) void scanB(const int* __restrict__ blockSums,
        int* __restrict__ blockOffs) {
    int t = threadIdx.x;
    int lane = t & 63, wid = t >> 6;
    int v = (t < SCAN_BLOCKS) ? blockSums[t] : 0;
    int s = v;
    #pragma unroll
    for (int m = 1; m < 64; m <<= 1) {
        int u = __shfl_up(s, m, 64);
        if (lane >= m) s += u;
    }
    __shared__ int wsum[4];
    if (lane == 63) wsum[wid] = s;
    __syncthreads();
    int off = 0;
    for (int w = 0; w < wid; ++w) off += wsum[w];
    blockOffs[t] = off + s - v;
}

__global__ __launch_bounds__(256) void scanC(const int* __restrict__ blockOffs,
        int* __restrict__ rowStart, int* __restrict__ cursor) {
    int i = blockIdx.x * 256 + threadIdx.x;
    if (i < N_NODES) {
        int v = rowStart[i] + blockOffs[blockIdx.x];
        rowStart[i] = v;
        cursor[i] = v;
    }
    if (i == 0) rowStart[N_NODES] = N_EDGES;
}

__global__ __launch_bounds__(256) void fill_kernel(const int* __restrict__ ei,
        const float* __restrict__ ew, int* __restrict__ cursor,
        int2* __restrict__ sSW) {
    int e = blockIdx.x * 256 + threadIdx.x;
    int s = ei[e];
    int d = ei[N_EDGES + e];
    float w = ew[e];
    int idx = atomicAdd(&cursor[d], 1);
    sSW[idx] = make_int2(s, __float_as_int(w));
}

// ---------------- MFMA GEMMs (bf16x3 split: hh + hl + lh) ----------------
// wave = 32 rows x BN cols; A/B frags straight from global (16B/lane).
// A: lane holds x[rBase + (lane&15)][kb + (lane>>4)*8 + j]
// B: lane holds W[ct*16 + (lane&15)][kb + (lane>>4)*8 + j]   (col-major planes)
// C/D: col = lane&15, row = (lane>>4)*4 + reg   [HW-verified]

// hl = h0@W0l^T + b0l (cols 0..127); agg = h0@W0r^T (cols 128..255)
__global__ __launch_bounds__(256) void gemm1_kernel(
        const unsigned short* __restrict__ h0h, const unsigned short* __restrict__ h0l,
        const unsigned short* __restrict__ Wt1h, const unsigned short* __restrict__ Wt1l,
        const float* __restrict__ b0l,
        float* __restrict__ hl, float* __restrict__ agg) {
    int wid = threadIdx.x >> 6, lane = threadIdx.x & 63;
    int rBase = (blockIdx.x * 4 + wid) * 32;
    if (rBase >= N_NODES) return;
    int cBase = blockIdx.y * 128;
    int lr = lane & 15;
    int lk = (lane >> 4) * 8;
    const unsigned short* a0h = h0h + (size_t)(rBase + lr) * 128 + lk;
    const unsigned short* a0l = h0l + (size_t)(rBase + lr) * 128 + lk;
    const unsigned short* a1h = a0h + 16 * 128;
    const unsigned short* a1l = a0l + 16 * 128;
    f32x4 acc[2][8] = {};
    #pragma unroll
    for (int ks = 0; ks < 4; ++ks) {
        int kb = ks * 32;
        short8 A0h = *(const short8*)(a0h + kb);
        short8 A0l = *(const short8*)(a0l + kb);
        short8 A1h = *(const short8*)(a1h + kb);
        short8 A1l = *(const short8*)(a1l + kb);
        #pragma unroll
        for (int ct = 0; ct < 8; ++ct) {
            size_t boff = (size_t)(cBase + ct * 16 + lr) * 128 + lk + kb;
            short8 Bh = *(const short8*)(Wt1h + boff);
            short8 Bl = *(const short8*)(Wt1l + boff);
            acc[0][ct] = __builtin_amdgcn_mfma_f32_16x16x32_bf16(A0h, Bh, acc[0][ct], 0, 0, 0);
            acc[0][ct] = __builtin_amdgcn_mfma_f32_16x16x32_bf16(A0h, Bl, acc[0][ct], 0, 0, 0);
            acc[0][ct] = __builtin_amdgcn_mfma_f32_16x16x32_bf16(A0l, Bh, acc[0][ct], 0, 0, 0);
            acc[1][ct] = __builtin_amdgcn_mfma_f32_16x16x32_bf16(A1h, Bh, acc[1][ct], 0, 0, 0);
            acc[1][ct] = __builtin_amdgcn_mfma_f32_16x16x32_bf16(A1h, Bl, acc[1][ct], 0, 0, 0);
            acc[1][ct] = __builtin_amdgcn_mfma_f32_16x16x32_bf16(A1l, Bh, acc[1][ct], 0, 0, 0);
        }
    }
    int orow = (lane >> 4) * 4;
    #pragma unroll
    for (int rt = 0; rt < 2; ++rt) {
        int row = rBase + rt * 16 + orow;
        #pragma unroll
        for (int ct = 0; ct < 8; ++ct) {
            int col = cBase + ct * 16 + lr;
            if (col < 128) {
                float bias = b0l[col];
                #pragma unroll
                for (int j = 0; j < 4; ++j)
                    hl[(size_t)(row + j) * 128 + col] = acc[rt][ct][j] + bias;
            } else {
                int cc = col - 128;
                #pragma unroll
                for (int j = 0; j < 4; ++j)
                    agg[(size_t)(row + j) * 128 + cc] = acc[rt][ct][j];
            }
        }
    }
}

// gl = h2@W1l^T + b1l (cols 0..39); agg2 = h2@W1r^T (cols 40..79)
__global__ __launch_bounds__(256) void gemm2_kernel(
        const unsigned short* __restrict__ h2h, const unsigned short* __restrict__ h2l,
        const unsigned short* __restrict__ Wt2h, const unsigned short* __restrict__ Wt2l,
        const float* __restrict__ b1l,
        float* __restrict__ gl, float* __restrict__ agg2) {
    int wid = threadIdx.x >> 6, lane = threadIdx.x & 63;
    int rBase = (blockIdx.x * 4 + wid) * 32;
    if (rBase >= N_NODES) return;
    int lr = lane & 15;
    int lk = (lane >> 4) * 8;
    const unsigned short* a0h = h2h + (size_t)(rBase + lr) * 128 + lk;
    const unsigned short* a0l = h2l + (size_t)(rBase + lr) * 128 + lk;
    const unsigned short* a1h = a0h + 16 * 128;
    const unsigned short* a1l = a0l + 16 * 128;
    f32x4 acc[2][5] = {};
    #pragma unroll
    for (int ks = 0; ks < 4; ++ks) {
        int kb = ks * 32;
        short8 A0h = *(const short8*)(a0h + kb);
        short8 A0l = *(const short8*)(a0l + kb);
        short8 A1h = *(const short8*)(a1h + kb);
        short8 A1l = *(const short8*)(a1l + kb);
        #pragma unroll
        for (int ct = 0; ct < 5; ++ct) {
            size_t boff = (size_t)(ct * 16 + lr) * 128 + lk + kb;
            short8 Bh = *(const short8*)(Wt2h + boff);
            short8 Bl = *(const short8*)(Wt2l + boff);
            acc[0][ct] = __builtin_amdgcn_mfma_f32_16x16x32_bf16(A0h, Bh, acc[0][ct], 0, 0, 0);
            acc[0][ct] = __builtin_amdgcn_mfma_f32_16x16x32_bf16(A0h, Bl, acc[0][ct], 0, 0, 0);
            acc[0][ct] = __builtin_amdgcn_mfma_f32_16x16x32_bf16(A0l, Bh, acc[0][ct], 0, 0, 0);
            acc[1][ct] = __builtin_amdgcn_mfma_f32_16x16x32_bf16(A1h, Bh, acc[1][ct], 0, 0, 0);
            acc[1][ct] = __builtin_amdgcn_mfma_f32_16x16x32_bf16(A1h, Bl, acc[1][ct], 0, 0, 0);
            acc[1][ct] = __builtin_amdgcn_mfma_f32_16x16x32_bf16(A1l, Bh, acc[1][ct], 0, 0, 0);
        }
    }
    int orow = (lane >> 4) * 4;
    #pragma unroll
    for (int rt = 0; rt < 2; ++rt) {
        int row = rBase + rt * 16 + orow;
        #pragma unroll
        for (int ct = 0; ct < 5; ++ct) {
            int col = ct * 16 + lr;   // 0..79
            if (col < 40) {
                float bias = b1l[col];
                #pragma unroll
                for (int j = 0; j < 4; ++j)
                    gl[(size_t)(row + j) * 40 + col] = acc[rt][ct][j] + bias;
            } else {
                int cc = col - 40;
                #pragma unroll
                for (int j = 0; j < 4; ++j)
                    agg2[(size_t)(row + j) * 40 + cc] = acc[rt][ct][j];
            }
        }
    }
}

// gather edges + fused l2norm+LN+relu, output split-bf16 h2 planes; wave per node
__global__ __launch_bounds__(256) void gather1_kernel(const int* __restrict__ rowStart,
        const int2* __restrict__ sSW, const float* __restrict__ hl,
        const float* __restrict__ agg,
        const float* __restrict__ g, const float* __restrict__ b,
        unsigned short* __restrict__ h2h, unsigned short* __restrict__ h2l) {
    int row = blockIdx.x * 4 + (threadIdx.x >> 6);
    int lane = threadIdx.x & 63;
    int beg = rowStart[row], end = rowStart[row + 1];
    float2 acc = ((const float2*)(agg + (size_t)row * 128))[lane];  // root term
    int e = beg;
    for (; e + 2 <= end; e += 2) {
        int2 p0 = sSW[e];
        int2 p1 = sSW[e + 1];
        float2 v0 = ((const float2*)(hl + (size_t)p0.x * 128))[lane];
        float2 v1 = ((const float2*)(hl + (size_t)p1.x * 128))[lane];
        float w0 = __int_as_float(p0.y), w1 = __int_as_float(p1.y);
        acc.x = fmaf(v0.x, w0, acc.x);
        acc.y = fmaf(v0.y, w0, acc.y);
        acc.x = fmaf(v1.x, w1, acc.x);
        acc.y = fmaf(v1.y, w1, acc.y);
    }
    if (e < end) {
        int2 p = sSW[e];
        float2 v = ((const float2*)(hl + (size_t)p.x * 128))[lane];
        float w = __int_as_float(p.y);
        acc.x = fmaf(v.x, w, acc.x);
        acc.y = fmaf(v.y, w, acc.y);
    }
    // fused: l2normalize -> LN -> relu -> bf16 hi/lo split
    float nrm = sqrtf(wave_sum(acc.x * acc.x + acc.y * acc.y));
    float inv = 1.0f / fmaxf(nrm, 1e-12f);
    float vx = acc.x * inv, vy = acc.y * inv;
    float mu = wave_sum(vx + vy) * (1.0f / 128.0f);
    float dx = vx - mu, dy = vy - mu;
    float var = wave_sum(dx * dx + dy * dy) * (1.0f / 128.0f);
    float rs = rsqrtf(var + 1e-5f);
    float2 gv = ((const float2*)g)[lane];
    float2 bv = ((const float2*)b)[lane];
    float ox = fmaxf(dx * rs * gv.x + bv.x, 0.0f);
    float oy = fmaxf(dy * rs * gv.y + bv.y, 0.0f);
    ushort2 hv, lv;
    hv.x = f2bf(ox); hv.y = f2bf(oy);
    lv.x = f2bf(ox - bf2f(hv.x)); lv.y = f2bf(oy - bf2f(hv.y));
    ((ushort2*)(h2h + (size_t)row * 128))[lane] = hv;
    ((ushort2*)(h2l + (size_t)row * 128))[lane] = lv;
}

// gather edges + fused l2norm + log_softmax; wave per node, lanes 0..39
__global__ __launch_bounds__(256) void gather2_kernel(const int* __restrict__ rowStart,
        const int2* __restrict__ sSW, const float* __restrict__ gl,
        const float* __restrict__ agg2, float* __restrict__ out) {
    int row = blockIdx.x * 4 + (threadIdx.x >> 6);
    int lane = threadIdx.x & 63;
    bool act = lane < 40;
    int beg = rowStart[row], end = rowStart[row + 1];
    float acc = act ? agg2[(size_t)row * 40 + lane] : 0.0f;  // root term
    int e = beg;
    for (; e + 2 <= end; e += 2) {
        int2 p0 = sSW[e];
        int2 p1 = sSW[e + 1];
        float v0 = gl[(size_t)p0.x * 40 + lane];   // lanes>=40 read in-bounds junk
        float v1 = gl[(size_t)p1.x * 40 + lane];
        acc = fmaf(v0, __int_as_float(p0.y), acc);
        acc = fmaf(v1, __int_as_float(p1.y), acc);
    }
    if (e < end) {
        int2 p = sSW[e];
        float v = gl[(size_t)p.x * 40 + lane];
        acc = fmaf(v, __int_as_float(p.y), acc);
    }
    float nrm = sqrtf(wave_sum(act ? acc * acc : 0.0f));
    float o = acc / fmaxf(nrm, 1e-12f);
    float m = wave_max(act ? o : -INFINITY);
    float s = wave_sum(act ? expf(o - m) : 0.0f);
    float ls = logf(s);
    if (act) out[(size_t)row * 40 + lane] = o - m - ls;
}

extern "C" void kernel_launch(void* const* d_in, const int* in_sizes, int n_in,
                              void* d_out, int out_size, void* d_ws, size_t ws_size,
                              hipStream_t stream) {
    const float* x    = (const float*)d_in[0];
    const int*   ei   = (const int*)d_in[1];
    const float* ew   = (const float*)d_in[2];
    const float* ln0g = (const float*)d_in[3];
    const float* ln0b = (const float*)d_in[4];
    const float* W0l  = (const float*)d_in[5];
    const float* b0l  = (const float*)d_in[6];
    const float* W0r  = (const float*)d_in[7];
    const float* ln1g = (const float*)d_in[8];
    const float* ln1b = (const float*)d_in[9];
    const float* W1l  = (const float*)d_in[10];
    const float* b1l  = (const float*)d_in[11];
    const float* W1r  = (const float*)d_in[12];
    float* out = (float*)d_out;

    float* ws = (float*)d_ws;
    const size_t NBUF = (size_t)N_NODES * 128;  // 5.12M
    float* hl  = ws;                  // [40000][128] fp32; later aliased as gl
    float* agg = hl + NBUF;           // [40000][128] fp32; later aliased as agg2
    float* gl   = hl;                 // [40000][40]  (hl dead after gather1)
    float* agg2 = agg;                // [40000][40]  (agg dead after gather1)
    unsigned short* h0h = (unsigned short*)(agg + NBUF);  // [40000][128] bf16 hi (reused as h2h)
    unsigned short* h0l = h0h + NBUF;                     // bf16 lo (reused as h2l)
    unsigned short* Wt1h = h0l + NBUF;                    // [256][128]
    unsigned short* Wt1l = Wt1h + 256 * 128;
    unsigned short* Wt2h = Wt1l + 256 * 128;              // [80][128]
    unsigned short* Wt2l = Wt2h + 80 * 128;
    int2* sSW = (int2*)(Wt2l + 80 * 128);                 // 8B-aligned (even ushort count)
    int*  deg       = (int*)(sSW + N_EDGES);
    int*  rowStart  = deg + N_NODES;            // N_NODES+1
    int*  cursor    = rowStart + N_NODES + 1;
    int*  blockSums = cursor + N_NODES;
    int*  blockOffs = blockSums + 256;

    // --- CSR build (shared by both conv layers) ---
    zero_deg<<<SCAN_BLOCKS, 256, 0, stream>>>(deg);
    deg_kernel<<<N_EDGES / 256, 256, 0, stream>>>(ei, deg);
    scanA<<<SCAN_BLOCKS, 256, 0, stream>>>(deg, rowStart, blockSums);
    scanB<<<1, 256, 0, stream>>>(blockSums, blockOffs);
    scanC<<<SCAN_BLOCKS, 256, 0, stream>>>(blockOffs, rowStart, cursor);
    fill_kernel<<<N_EDGES / 256, 256, 0, stream>>>(ei, ew, cursor, sSW);

    // --- pipeline ---
    ln0_kernel<<<N_NODES / 4, 256, 0, stream>>>(x, ln0g, ln0b, h0h, h0l);
    prep_w<<<(256 * 128 + 80 * 128) / 256, 256, 0, stream>>>(W0l, W0r, W1l, W1r,
                                                             Wt1h, Wt1l, Wt2h, Wt2l);
    gemm1_kernel<<<dim3(313, 2), 256, 0, stream>>>(h0h, h0l, Wt1h, Wt1l, b0l, hl, agg);
    gather1_kernel<<<N_NODES / 4, 256, 0, stream>>>(rowStart, sSW, hl, agg,
                                                    ln1g, ln1b, h0h, h0l);
    gemm2_kernel<<<313, 256, 0, stream>>>(h0h, h0l, Wt2h, Wt2l, b1l, gl, agg2);
    gather2_kernel<<<N_NODES / 4, 256, 0, stream>>>(rowStart, sSW, gl, agg2, out);
}

// Round 3
// 213.386 us; speedup vs baseline: 3.7935x; 1.1218x over previous
//
#include <hip/hip_runtime.h>
#include <math.h>

#define N_NODES 40000
#define N_EDGES 640000
#define SCAN_BLOCKS ((N_NODES + 255) / 256)   // 157

typedef __attribute__((ext_vector_type(8))) short short8;   // 8 bf16 (A/B frag)
typedef __attribute__((ext_vector_type(4))) float f32x4;    // C/D frag

__device__ __forceinline__ unsigned short f2bf(float f) {
    union { float f; unsigned u; } v; v.f = f;
    unsigned r = (v.u + 0x7FFFu + ((v.u >> 16) & 1u)) >> 16;  // RNE
    return (unsigned short)r;
}
__device__ __forceinline__ float bf2f(unsigned short h) {
    union { unsigned u; float f; } v; v.u = ((unsigned)h) << 16;
    return v.f;
}

__device__ __forceinline__ float wave_sum(float v) {
    #pragma unroll
    for (int m = 1; m < 64; m <<= 1) v += __shfl_xor(v, m, 64);
    return v;
}
__device__ __forceinline__ float wave_max(float v) {
    #pragma unroll
    for (int m = 1; m < 64; m <<= 1) v = fmaxf(v, __shfl_xor(v, m, 64));
    return v;
}

// Fused: blocks [0,10000): h0 = LN(x) -> bf16 hi/lo planes
//        blocks [10000,10168): weight transpose+split
//        blocks [10168,10325): zero deg
__global__ __launch_bounds__(256) void combo0_kernel(const float* __restrict__ x,
        const float* __restrict__ g, const float* __restrict__ b,
        unsigned short* __restrict__ h0h, unsigned short* __restrict__ h0l,
        const float* __restrict__ W0l, const float* __restrict__ W0r,
        const float* __restrict__ W1l, const float* __restrict__ W1r,
        unsigned short* __restrict__ Wt1h, unsigned short* __restrict__ Wt1l,
        unsigned short* __restrict__ Wt2h, unsigned short* __restrict__ Wt2l,
        int* __restrict__ deg) {
    int bid = blockIdx.x;
    if (bid < 10000) {
        int row = bid * 4 + (threadIdx.x >> 6);
        int lane = threadIdx.x & 63;
        float2 v = ((const float2*)(x + (size_t)row * 128))[lane];
        float mu = wave_sum(v.x + v.y) * (1.0f / 128.0f);
        float dx = v.x - mu, dy = v.y - mu;
        float var = wave_sum(dx * dx + dy * dy) * (1.0f / 128.0f);
        float rs = rsqrtf(var + 1e-5f);
        float2 gv = ((const float2*)g)[lane];
        float2 bv = ((const float2*)b)[lane];
        float ox = dx * rs * gv.x + bv.x;
        float oy = dy * rs * gv.y + bv.y;
        ushort2 hv, lv;
        hv.x = f2bf(ox); hv.y = f2bf(oy);
        lv.x = f2bf(ox - bf2f(hv.x)); lv.y = f2bf(oy - bf2f(hv.y));
        ((ushort2*)(h0h + (size_t)row * 128))[lane] = hv;
        ((ushort2*)(h0l + (size_t)row * 128))[lane] = lv;
    } else if (bid < 10168) {
        int i = (bid - 10000) * 256 + threadIdx.x;   // 0..43007
        float w; unsigned short *ph, *pl; int idx;
        if (i < 256 * 128) {
            int c = i >> 7, k = i & 127;
            w = (c < 128) ? W0l[c * 128 + k] : W0r[(c - 128) * 128 + k];
            ph = Wt1h; pl = Wt1l; idx = i;
        } else {
            int j = i - 256 * 128;
            int c = j >> 7, k = j & 127;
            w = (c < 40) ? W1l[c * 128 + k] : W1r[(c - 40) * 128 + k];
            ph = Wt2h; pl = Wt2l; idx = j;
        }
        unsigned short hi = f2bf(w);
        ph[idx] = hi;
        pl[idx] = f2bf(w - bf2f(hi));
    } else {
        int i = (bid - 10168) * 256 + threadIdx.x;
        if (i < N_NODES) deg[i] = 0;
    }
}

// ---------------- CSR-by-destination build ----------------

__global__ __launch_bounds__(256) void deg_kernel(const int* __restrict__ ei,
        int* __restrict__ deg) {
    int e = blockIdx.x * 256 + threadIdx.x;
    atomicAdd(&deg[ei[N_EDGES + e]], 1);
}

__global__ __launch_bounds__(256) void scanA(const int* __restrict__ deg,
        int* __restrict__ rowStart, int* __restrict__ blockSums) {
    int i = blockIdx.x * 256 + threadIdx.x;
    int lane = threadIdx.x & 63, wid = threadIdx.x >> 6;
    int v = (i < N_NODES) ? deg[i] : 0;
    int s = v;
    #pragma unroll
    for (int m = 1; m < 64; m <<= 1) {
        int u = __shfl_up(s, m, 64);
        if (lane >= m) s += u;
    }
    __shared__ int wsum[4];
    if (lane == 63) wsum[wid] = s;
    __syncthreads();
    int off = 0;
    for (int w = 0; w < wid; ++w) off += wsum[w];
    if (i < N_NODES) rowStart[i] = off + s - v;
    if (threadIdx.x == 255) blockSums[blockIdx.x] = off + s;
}

__global__ __launch_bounds__(256) void scanB(const int* __restrict__ blockSums,
        int* __restrict__ blockOffs) {
    int t = threadIdx.x;
    int lane = t & 63, wid = t >> 6;
    int v = (t < SCAN_BLOCKS) ? blockSums[t] : 0;
    int s = v;
    #pragma unroll
    for (int m = 1; m < 64; m <<= 1) {
        int u = __shfl_up(s, m, 64);
        if (lane >= m) s += u;
    }
    __shared__ int wsum[4];
    if (lane == 63) wsum[wid] = s;
    __syncthreads();
    int off = 0;
    for (int w = 0; w < wid; ++w) off += wsum[w];
    blockOffs[t] = off + s - v;
}

__global__ __launch_bounds__(256) void scanC(const int* __restrict__ blockOffs,
        int* __restrict__ rowStart, int* __restrict__ cursor) {
    int i = blockIdx.x * 256 + threadIdx.x;
    if (i < N_NODES) {
        int v = rowStart[i] + blockOffs[blockIdx.x];
        rowStart[i] = v;
        cursor[i] = v;
    }
    if (i == 0) rowStart[N_NODES] = N_EDGES;
}

// bucket-fill packed edges: low16 = src, high16 = bf16(weight)
__global__ __launch_bounds__(256) void fill_kernel(const int* __restrict__ ei,
        const float* __restrict__ ew, int* __restrict__ cursor,
        unsigned int* __restrict__ sPk) {
    int e = blockIdx.x * 256 + threadIdx.x;
    int s = ei[e];
    int d = ei[N_EDGES + e];
    unsigned int pk = (unsigned int)s | ((unsigned int)f2bf(ew[e]) << 16);
    int idx = atomicAdd(&cursor[d], 1);
    sPk[idx] = pk;
}

// ---------------- MFMA GEMMs (bf16x3 split: hh + hl + lh) ----------------
// A: lane holds x[rBase + (lane&15)][kb + (lane>>4)*8 + j]
// B: lane holds W[ct*16 + (lane&15)][kb + (lane>>4)*8 + j]   (col-major planes)
// C/D: col = lane&15, row = (lane>>4)*4 + reg   [HW-verified]

// hl(bf16, bias folded) = h0@W0l^T + b0l (cols 0..127); agg(fp32) = h0@W0r^T
__global__ __launch_bounds__(256) void gemm1_kernel(
        const unsigned short* __restrict__ h0h, const unsigned short* __restrict__ h0l,
        const unsigned short* __restrict__ Wt1h, const unsigned short* __restrict__ Wt1l,
        const float* __restrict__ b0l,
        unsigned short* __restrict__ hl, float* __restrict__ agg) {
    int wid = threadIdx.x >> 6, lane = threadIdx.x & 63;
    int rBase = (blockIdx.x * 4 + wid) * 32;
    if (rBase >= N_NODES) return;
    int cBase = blockIdx.y * 128;
    int lr = lane & 15;
    int lk = (lane >> 4) * 8;
    const unsigned short* a0h = h0h + (size_t)(rBase + lr) * 128 + lk;
    const unsigned short* a0l = h0l + (size_t)(rBase + lr) * 128 + lk;
    const unsigned short* a1h = a0h + 16 * 128;
    const unsigned short* a1l = a0l + 16 * 128;
    f32x4 acc[2][8] = {};
    #pragma unroll
    for (int ks = 0; ks < 4; ++ks) {
        int kb = ks * 32;
        short8 A0h = *(const short8*)(a0h + kb);
        short8 A0l = *(const short8*)(a0l + kb);
        short8 A1h = *(const short8*)(a1h + kb);
        short8 A1l = *(const short8*)(a1l + kb);
        #pragma unroll
        for (int ct = 0; ct < 8; ++ct) {
            size_t boff = (size_t)(cBase + ct * 16 + lr) * 128 + lk + kb;
            short8 Bh = *(const short8*)(Wt1h + boff);
            short8 Bl = *(const short8*)(Wt1l + boff);
            acc[0][ct] = __builtin_amdgcn_mfma_f32_16x16x32_bf16(A0h, Bh, acc[0][ct], 0, 0, 0);
            acc[0][ct] = __builtin_amdgcn_mfma_f32_16x16x32_bf16(A0h, Bl, acc[0][ct], 0, 0, 0);
            acc[0][ct] = __builtin_amdgcn_mfma_f32_16x16x32_bf16(A0l, Bh, acc[0][ct], 0, 0, 0);
            acc[1][ct] = __builtin_amdgcn_mfma_f32_16x16x32_bf16(A1h, Bh, acc[1][ct], 0, 0, 0);
            acc[1][ct] = __builtin_amdgcn_mfma_f32_16x16x32_bf16(A1h, Bl, acc[1][ct], 0, 0, 0);
            acc[1][ct] = __builtin_amdgcn_mfma_f32_16x16x32_bf16(A1l, Bh, acc[1][ct], 0, 0, 0);
        }
    }
    int orow = (lane >> 4) * 4;
    #pragma unroll
    for (int rt = 0; rt < 2; ++rt) {
        int row = rBase + rt * 16 + orow;
        #pragma unroll
        for (int ct = 0; ct < 8; ++ct) {
            int col = cBase + ct * 16 + lr;
            if (col < 128) {
                float bias = b0l[col];
                #pragma unroll
                for (int j = 0; j < 4; ++j)
                    hl[(size_t)(row + j) * 128 + col] = f2bf(acc[rt][ct][j] + bias);
            } else {
                int cc = col - 128;
                #pragma unroll
                for (int j = 0; j < 4; ++j)
                    agg[(size_t)(row + j) * 128 + cc] = acc[rt][ct][j];
            }
        }
    }
}

// gl(bf16, bias folded) = h2@W1l^T + b1l (cols 0..39); agg2(fp32) = h2@W1r^T
__global__ __launch_bounds__(256) void gemm2_kernel(
        const unsigned short* __restrict__ h2h, const unsigned short* __restrict__ h2l,
        const unsigned short* __restrict__ Wt2h, const unsigned short* __restrict__ Wt2l,
        const float* __restrict__ b1l,
        unsigned short* __restrict__ gl, float* __restrict__ agg2) {
    int wid = threadIdx.x >> 6, lane = threadIdx.x & 63;
    int rBase = (blockIdx.x * 4 + wid) * 32;
    if (rBase >= N_NODES) return;
    int lr = lane & 15;
    int lk = (lane >> 4) * 8;
    const unsigned short* a0h = h2h + (size_t)(rBase + lr) * 128 + lk;
    const unsigned short* a0l = h2l + (size_t)(rBase + lr) * 128 + lk;
    const unsigned short* a1h = a0h + 16 * 128;
    const unsigned short* a1l = a0l + 16 * 128;
    f32x4 acc[2][5] = {};
    #pragma unroll
    for (int ks = 0; ks < 4; ++ks) {
        int kb = ks * 32;
        short8 A0h = *(const short8*)(a0h + kb);
        short8 A0l = *(const short8*)(a0l + kb);
        short8 A1h = *(const short8*)(a1h + kb);
        short8 A1l = *(const short8*)(a1l + kb);
        #pragma unroll
        for (int ct = 0; ct < 5; ++ct) {
            size_t boff = (size_t)(ct * 16 + lr) * 128 + lk + kb;
            short8 Bh = *(const short8*)(Wt2h + boff);
            short8 Bl = *(const short8*)(Wt2l + boff);
            acc[0][ct] = __builtin_amdgcn_mfma_f32_16x16x32_bf16(A0h, Bh, acc[0][ct], 0, 0, 0);
            acc[0][ct] = __builtin_amdgcn_mfma_f32_16x16x32_bf16(A0h, Bl, acc[0][ct], 0, 0, 0);
            acc[0][ct] = __builtin_amdgcn_mfma_f32_16x16x32_bf16(A0l, Bh, acc[0][ct], 0, 0, 0);
            acc[1][ct] = __builtin_amdgcn_mfma_f32_16x16x32_bf16(A1h, Bh, acc[1][ct], 0, 0, 0);
            acc[1][ct] = __builtin_amdgcn_mfma_f32_16x16x32_bf16(A1h, Bl, acc[1][ct], 0, 0, 0);
            acc[1][ct] = __builtin_amdgcn_mfma_f32_16x16x32_bf16(A1l, Bh, acc[1][ct], 0, 0, 0);
        }
    }
    int orow = (lane >> 4) * 4;
    #pragma unroll
    for (int rt = 0; rt < 2; ++rt) {
        int row = rBase + rt * 16 + orow;
        #pragma unroll
        for (int ct = 0; ct < 5; ++ct) {
            int col = ct * 16 + lr;   // 0..79
            if (col < 40) {
                float bias = b1l[col];
                #pragma unroll
                for (int j = 0; j < 4; ++j)
                    gl[(size_t)(row + j) * 40 + col] = f2bf(acc[rt][ct][j] + bias);
            } else {
                int cc = col - 40;
                #pragma unroll
                for (int j = 0; j < 4; ++j)
                    agg2[(size_t)(row + j) * 40 + cc] = acc[rt][ct][j];
            }
        }
    }
}

__device__ __forceinline__ void acc_edge1(const unsigned short* __restrict__ hl,
        unsigned int pk, int lane, float2* acc) {
    int s = pk & 0xFFFF;
    float w = bf2f((unsigned short)(pk >> 16));
    ushort2 u = ((const ushort2*)(hl + (size_t)s * 128))[lane];
    acc->x = fmaf(bf2f(u.x), w, acc->x);
    acc->y = fmaf(bf2f(u.y), w, acc->y);
}

// gather bf16 messages + fused l2norm+LN+relu -> split-bf16 h2; wave per node
__global__ __launch_bounds__(256) void gather1_kernel(const int* __restrict__ rowStart,
        const unsigned int* __restrict__ sPk, const unsigned short* __restrict__ hl,
        const float* __restrict__ agg,
        const float* __restrict__ g, const float* __restrict__ b,
        unsigned short* __restrict__ h2h, unsigned short* __restrict__ h2l) {
    int row = blockIdx.x * 4 + (threadIdx.x >> 6);
    int lane = threadIdx.x & 63;
    int beg = rowStart[row], end = rowStart[row + 1];
    float2 acc = ((const float2*)(agg + (size_t)row * 128))[lane];  // root term
    int e = beg;
    for (; e + 4 <= end; e += 4) {
        unsigned int p0 = sPk[e], p1 = sPk[e + 1], p2 = sPk[e + 2], p3 = sPk[e + 3];
        acc_edge1(hl, p0, lane, &acc);
        acc_edge1(hl, p1, lane, &acc);
        acc_edge1(hl, p2, lane, &acc);
        acc_edge1(hl, p3, lane, &acc);
    }
    for (; e < end; ++e) acc_edge1(hl, sPk[e], lane, &acc);
    // fused: l2normalize -> LN -> relu -> bf16 hi/lo split
    float nrm = sqrtf(wave_sum(acc.x * acc.x + acc.y * acc.y));
    float inv = 1.0f / fmaxf(nrm, 1e-12f);
    float vx = acc.x * inv, vy = acc.y * inv;
    float mu = wave_sum(vx + vy) * (1.0f / 128.0f);
    float dx = vx - mu, dy = vy - mu;
    float var = wave_sum(dx * dx + dy * dy) * (1.0f / 128.0f);
    float rs = rsqrtf(var + 1e-5f);
    float2 gv = ((const float2*)g)[lane];
    float2 bv = ((const float2*)b)[lane];
    float ox = fmaxf(dx * rs * gv.x + bv.x, 0.0f);
    float oy = fmaxf(dy * rs * gv.y + bv.y, 0.0f);
    ushort2 hv, lv;
    hv.x = f2bf(ox); hv.y = f2bf(oy);
    lv.x = f2bf(ox - bf2f(hv.x)); lv.y = f2bf(oy - bf2f(hv.y));
    ((ushort2*)(h2h + (size_t)row * 128))[lane] = hv;
    ((ushort2*)(h2l + (size_t)row * 128))[lane] = lv;
}

// gather bf16 messages + fused l2norm + log_softmax; wave per node, lanes 0..39
__global__ __launch_bounds__(256) void gather2_kernel(const int* __restrict__ rowStart,
        const unsigned int* __restrict__ sPk, const unsigned short* __restrict__ gl,
        const float* __restrict__ agg2, float* __restrict__ out) {
    int row = blockIdx.x * 4 + (threadIdx.x >> 6);
    int lane = threadIdx.x & 63;
    bool act = lane < 40;
    int beg = rowStart[row], end = rowStart[row + 1];
    float acc = act ? agg2[(size_t)row * 40 + lane] : 0.0f;  // root term
    int e = beg;
    for (; e + 2 <= end; e += 2) {
        unsigned int p0 = sPk[e], p1 = sPk[e + 1];
        if (act) {
            float v0 = bf2f(gl[(size_t)(p0 & 0xFFFF) * 40 + lane]);
            float v1 = bf2f(gl[(size_t)(p1 & 0xFFFF) * 40 + lane]);
            acc = fmaf(v0, bf2f((unsigned short)(p0 >> 16)), acc);
            acc = fmaf(v1, bf2f((unsigned short)(p1 >> 16)), acc);
        }
    }
    if (e < end) {
        unsigned int p = sPk[e];
        if (act) {
            float v = bf2f(gl[(size_t)(p & 0xFFFF) * 40 + lane]);
            acc = fmaf(v, bf2f((unsigned short)(p >> 16)), acc);
        }
    }
    float nrm = sqrtf(wave_sum(act ? acc * acc : 0.0f));
    float o = acc / fmaxf(nrm, 1e-12f);
    float m = wave_max(act ? o : -INFINITY);
    float s = wave_sum(act ? expf(o - m) : 0.0f);
    float ls = logf(s);
    if (act) out[(size_t)row * 40 + lane] = o - m - ls;
}

extern "C" void kernel_launch(void* const* d_in, const int* in_sizes, int n_in,
                              void* d_out, int out_size, void* d_ws, size_t ws_size,
                              hipStream_t stream) {
    const float* x    = (const float*)d_in[0];
    const int*   ei   = (const int*)d_in[1];
    const float* ew   = (const float*)d_in[2];
    const float* ln0g = (const float*)d_in[3];
    const float* ln0b = (const float*)d_in[4];
    const float* W0l  = (const float*)d_in[5];
    const float* b0l  = (const float*)d_in[6];
    const float* W0r  = (const float*)d_in[7];
    const float* ln1g = (const float*)d_in[8];
    const float* ln1b = (const float*)d_in[9];
    const float* W1l  = (const float*)d_in[10];
    const float* b1l  = (const float*)d_in[11];
    const float* W1r  = (const float*)d_in[12];
    float* out = (float*)d_out;

    const size_t NBUF = (size_t)N_NODES * 128;  // 5.12M elems
    char* p = (char*)d_ws;
    auto alloc = [&](size_t bytes) { char* r = p; p += (bytes + 255) & ~(size_t)255; return r; };
    float*          agg  = (float*)alloc(NBUF * 4);          // agg / agg2 (fp32)
    unsigned short* hl   = (unsigned short*)alloc(NBUF * 2); // hl / gl (bf16)
    unsigned short* h0h  = (unsigned short*)alloc(NBUF * 2); // h0 hi / h2 hi
    unsigned short* h0l  = (unsigned short*)alloc(NBUF * 2); // h0 lo / h2 lo
    unsigned short* Wt1h = (unsigned short*)alloc(256 * 128 * 2);
    unsigned short* Wt1l = (unsigned short*)alloc(256 * 128 * 2);
    unsigned short* Wt2h = (unsigned short*)alloc(80 * 128 * 2);
    unsigned short* Wt2l = (unsigned short*)alloc(80 * 128 * 2);
    unsigned int*   sPk  = (unsigned int*)alloc((size_t)N_EDGES * 4);
    int*            deg  = (int*)alloc(N_NODES * 4);
    int*       rowStart  = (int*)alloc((N_NODES + 1) * 4);
    int*         cursor  = (int*)alloc(N_NODES * 4);
    int*      blockSums  = (int*)alloc(256 * 4);
    int*      blockOffs  = (int*)alloc(256 * 4);
    unsigned short* gl   = hl;    // hl dead after gather1
    float*        agg2   = agg;   // agg dead after gather1

    // --- fused LN0 + weight prep + deg zero ---
    combo0_kernel<<<10000 + 168 + SCAN_BLOCKS, 256, 0, stream>>>(x, ln0g, ln0b,
            h0h, h0l, W0l, W0r, W1l, W1r, Wt1h, Wt1l, Wt2h, Wt2l, deg);
    // --- CSR build (shared by both conv layers) ---
    deg_kernel<<<N_EDGES / 256, 256, 0, stream>>>(ei, deg);
    scanA<<<SCAN_BLOCKS, 256, 0, stream>>>(deg, rowStart, blockSums);
    scanB<<<1, 256, 0, stream>>>(blockSums, blockOffs);
    scanC<<<SCAN_BLOCKS, 256, 0, stream>>>(blockOffs, rowStart, cursor);
    fill_kernel<<<N_EDGES / 256, 256, 0, stream>>>(ei, ew, cursor, sPk);

    // --- pipeline ---
    gemm1_kernel<<<dim3(313, 2), 256, 0, stream>>>(h0h, h0l, Wt1h, Wt1l, b0l, hl, agg);
    gather1_kernel<<<N_NODES / 4, 256, 0, stream>>>(rowStart, sPk, hl, agg,
                                                    ln1g, ln1b, h0h, h0l);
    gemm2_kernel<<<313, 256, 0, stream>>>(h0h, h0l, Wt2h, Wt2l, b1l, gl, agg2);
    gather2_kernel<<<N_NODES / 4, 256, 0, stream>>>(rowStart, sPk, gl, agg2, out);
}